// Round 1
// baseline (80.711 us; speedup 1.0000x reference)
//
#include <hip/hip_runtime.h>
#include <hip/hip_bf16.h>
#include <math.h>

// Problem constants (from reference): B=2, P=10000, L=64, E=100
#define B_DIM 2
#define P_TOT 10000
#define L_DIM 64
#define E_DIM 100
#define THRESH 0.001f

// ---------------------------------------------------------------------------
// Kernel 1: fold all per-(b,e) math into 3 coefficients.
//   term(b,p,l,e) = F_bright * exp(-d2/(2 rho^2 Fsize) + sens/(lam^2 Fstreak))
//                 = exp2( d2*cA + sens*cS + L2F )
//   cA = -log2(e) / (2 rho^2 Fsize)
//   cS =  log2(e) / (lam^2 Fstreak)
//   L2F = log2(F_bright)  (or -1e30 when F_bright == 0 -> exp2 -> 0)
// coeff[e*2 + b] = {cA, cS, L2F, 0}
// ---------------------------------------------------------------------------
__global__ void axon_precompute(const float* __restrict__ stim,
                                const float* __restrict__ params,
                                float4* __restrict__ coeff) {
    int i = threadIdx.x;
    if (i >= B_DIM * E_DIM) return;
    int e = i >> 1;
    int b = i & 1;

    float freq = stim[(b * E_DIM + e) * 3 + 0];
    float amp  = stim[(b * E_DIM + e) * 3 + 1];
    float pdur = stim[(b * E_DIM + e) * 3 + 2];

    const float* pp = params + b * 12;
    float rho = pp[0], axl = pp[1];
    float a0 = pp[2], a1 = pp[3], a2 = pp[4], a3 = pp[5];
    float a5 = pp[7], a6 = pp[8], a7 = pp[9], a8 = pp[10], a9 = pp[11];

    float scaled = (a1 + a0 * pdur) * amp;
    float Fb = a2 * scaled + a3 * freq;
    if (!(scaled > 0.25f)) Fb = 0.f;   // AMP_CUTOFF
    if (!(amp > 0.f))      Fb = 0.f;   // !LIKE_JAX

    float rho2 = rho * rho;
    float Fsize = fmaxf(a5 * scaled + a6, 100.f / rho2);
    float axl2 = axl * axl;
    float Fstreak = fmaxf(a9 - a7 * powf(pdur, a8), 100.f / axl2);

    const float LOG2E = 1.4426950408889634f;
    float cA = -LOG2E / (2.f * rho2 * Fsize);
    float cS =  LOG2E / (axl2 * Fstreak);
    float L2F = (Fb > 0.f) ? log2f(Fb) : -1e30f;

    coeff[e * 2 + b] = make_float4(cA, cS, L2F, 0.f);
}

// ---------------------------------------------------------------------------
// Kernel 2: one wave per pixel p, one lane per axon segment l.
// Each lane streams d2_el[p][l][0..99] (25 x float4), accumulates both
// batches' sums, then a 64-lane shfl_xor max-reduction over l.
// ---------------------------------------------------------------------------
__global__ __launch_bounds__(256) void axon_main(
    const float* __restrict__ d2_el,
    const float* __restrict__ axon_contrib,
    const float4* __restrict__ coeff,
    float* __restrict__ out) {

    __shared__ float4 sc[E_DIM * B_DIM];   // 200 float4 = 3.2 KB

    int tid = threadIdx.x;
    if (tid < E_DIM * B_DIM) sc[tid] = coeff[tid];
    __syncthreads();

    int wave = tid >> 6;
    int lane = tid & 63;
    int p = blockIdx.x * 4 + wave;          // 2500 blocks * 4 waves = 10000
    int l = lane;

    size_t row_idx = ((size_t)p * L_DIM + l);
    const float4* row = (const float4*)(d2_el + row_idx * E_DIM); // 400B-aligned
    float sens = axon_contrib[row_idx * 3 + 2];

    float sum0 = 0.f, sum1 = 0.f;

    #pragma unroll 5
    for (int j = 0; j < E_DIM / 4; ++j) {
        float4 d2v = row[j];
        #pragma unroll
        for (int k = 0; k < 4; ++k) {
            int e = j * 4 + k;
            float d2 = (k == 0) ? d2v.x : (k == 1) ? d2v.y : (k == 2) ? d2v.z : d2v.w;
            float4 c0 = sc[e * 2 + 0];
            float4 c1 = sc[e * 2 + 1];
            sum0 += __builtin_amdgcn_exp2f(fmaf(d2, c0.x, fmaf(sens, c0.y, c0.z)));
            sum1 += __builtin_amdgcn_exp2f(fmaf(d2, c1.x, fmaf(sens, c1.y, c1.z)));
        }
    }

    // max over l = 64-lane reduction
    #pragma unroll
    for (int off = 32; off; off >>= 1) {
        sum0 = fmaxf(sum0, __shfl_xor(sum0, off, 64));
        sum1 = fmaxf(sum1, __shfl_xor(sum1, off, 64));
    }

    if (lane == 0) {
        out[p]         = (sum0 > THRESH) ? sum0 : 0.f;
        out[P_TOT + p] = (sum1 > THRESH) ? sum1 : 0.f;
    }
}

extern "C" void kernel_launch(void* const* d_in, const int* in_sizes, int n_in,
                              void* d_out, int out_size, void* d_ws, size_t ws_size,
                              hipStream_t stream) {
    const float* stim         = (const float*)d_in[0];  // (B,E,3)
    const float* params       = (const float*)d_in[1];  // (B,12)
    const float* axon_contrib = (const float*)d_in[2];  // (P,L,3)
    const float* d2_el        = (const float*)d_in[3];  // (P,L,E)
    float* out = (float*)d_out;                         // (B,P) = 20000 floats
    float4* coeff = (float4*)d_ws;                      // 200 float4 = 3200 B

    axon_precompute<<<1, 256, 0, stream>>>(stim, params, coeff);
    axon_main<<<P_TOT / 4, 256, 0, stream>>>(d2_el, axon_contrib, coeff, out);
}

// Round 2
// 71.187 us; speedup vs baseline: 1.1338x; 1.1338x over previous
//
#include <hip/hip_runtime.h>
#include <hip/hip_bf16.h>
#include <math.h>

// Problem constants (from reference): B=2, P=10000, L=64, E=100
#define B_DIM 2
#define P_TOT 10000
#define L_DIM 64
#define E_DIM 100
#define THRESH 0.001f

// ---------------------------------------------------------------------------
// Kernel 1: fold all per-(b,e) math into 3 coefficients.
//   term(b,p,l,e) = F_bright * exp(-d2/(2 rho^2 Fsize) + sens/(lam^2 Fstreak))
//                 = exp2( d2*cA + sens*cS + L2F )
// coeff[e*2 + b] = {cA, cS, L2F, 0}
// ---------------------------------------------------------------------------
__global__ void axon_precompute(const float* __restrict__ stim,
                                const float* __restrict__ params,
                                float4* __restrict__ coeff) {
    int i = threadIdx.x;
    if (i >= B_DIM * E_DIM) return;
    int e = i >> 1;
    int b = i & 1;

    float freq = stim[(b * E_DIM + e) * 3 + 0];
    float amp  = stim[(b * E_DIM + e) * 3 + 1];
    float pdur = stim[(b * E_DIM + e) * 3 + 2];

    const float* pp = params + b * 12;
    float rho = pp[0], axl = pp[1];
    float a0 = pp[2], a1 = pp[3], a2 = pp[4], a3 = pp[5];
    float a5 = pp[7], a6 = pp[8], a7 = pp[9], a8 = pp[10], a9 = pp[11];

    float scaled = (a1 + a0 * pdur) * amp;
    float Fb = a2 * scaled + a3 * freq;
    if (!(scaled > 0.25f)) Fb = 0.f;   // AMP_CUTOFF
    if (!(amp > 0.f))      Fb = 0.f;   // !LIKE_JAX

    float rho2 = rho * rho;
    float Fsize = fmaxf(a5 * scaled + a6, 100.f / rho2);
    float axl2 = axl * axl;
    float Fstreak = fmaxf(a9 - a7 * powf(pdur, a8), 100.f / axl2);

    const float LOG2E = 1.4426950408889634f;
    float cA = -LOG2E / (2.f * rho2 * Fsize);
    float cS =  LOG2E / (axl2 * Fstreak);
    float L2F = (Fb > 0.f) ? log2f(Fb) : -1e30f;

    coeff[e * 2 + b] = make_float4(cA, cS, L2F, 0.f);
}

// ---------------------------------------------------------------------------
// Kernel 2: one wave per pixel p, one lane per axon segment l.
// All 25 float4 row loads are issued back-to-back into registers FIRST
// (same-cache-line misses merge in MSHRs -> each HBM line fetched exactly
// once), then the compute loop runs from registers. Coefficients are read
// via uniform constant indices from global (scalar-cache path).
// ---------------------------------------------------------------------------
__global__ __launch_bounds__(256) void axon_main(
    const float* __restrict__ d2_el,
    const float* __restrict__ axon_contrib,
    const float4* __restrict__ coeff,
    float* __restrict__ out) {

    int tid  = threadIdx.x;
    int wave = tid >> 6;
    int lane = tid & 63;
    int p = blockIdx.x * 4 + wave;          // 2500 blocks * 4 waves = 10000

    size_t row_idx = ((size_t)p * L_DIM + lane);
    const float4* row = (const float4*)(d2_el + row_idx * E_DIM); // 400B rows
    float sens = axon_contrib[row_idx * 3 + 2];

    // ---- load phase: 25 back-to-back float4 loads (100 VGPRs) ----
    float4 d2r[E_DIM / 4];
    #pragma unroll
    for (int j = 0; j < E_DIM / 4; ++j) d2r[j] = row[j];

    // ---- compute phase: all indices compile-time constant ----
    float sum0 = 0.f, sum1 = 0.f;
    #pragma unroll
    for (int j = 0; j < E_DIM / 4; ++j) {
        #pragma unroll
        for (int k = 0; k < 4; ++k) {
            int e = j * 4 + k;
            float d2 = (k == 0) ? d2r[j].x : (k == 1) ? d2r[j].y
                     : (k == 2) ? d2r[j].z : d2r[j].w;
            float4 c0 = coeff[e * 2 + 0];   // uniform index -> s_load
            float4 c1 = coeff[e * 2 + 1];
            sum0 += __builtin_amdgcn_exp2f(fmaf(d2, c0.x, fmaf(sens, c0.y, c0.z)));
            sum1 += __builtin_amdgcn_exp2f(fmaf(d2, c1.x, fmaf(sens, c1.y, c1.z)));
        }
    }

    // max over l = 64-lane butterfly reduction
    #pragma unroll
    for (int off = 32; off; off >>= 1) {
        sum0 = fmaxf(sum0, __shfl_xor(sum0, off, 64));
        sum1 = fmaxf(sum1, __shfl_xor(sum1, off, 64));
    }

    if (lane == 0) {
        out[p]         = (sum0 > THRESH) ? sum0 : 0.f;
        out[P_TOT + p] = (sum1 > THRESH) ? sum1 : 0.f;
    }
}

extern "C" void kernel_launch(void* const* d_in, const int* in_sizes, int n_in,
                              void* d_out, int out_size, void* d_ws, size_t ws_size,
                              hipStream_t stream) {
    const float* stim         = (const float*)d_in[0];  // (B,E,3)
    const float* params       = (const float*)d_in[1];  // (B,12)
    const float* axon_contrib = (const float*)d_in[2];  // (P,L,3)
    const float* d2_el        = (const float*)d_in[3];  // (P,L,E)
    float* out = (float*)d_out;                         // (B,P) = 20000 floats
    float4* coeff = (float4*)d_ws;                      // 200 float4 = 3200 B

    axon_precompute<<<1, 256, 0, stream>>>(stim, params, coeff);
    axon_main<<<P_TOT / 4, 256, 0, stream>>>(d2_el, axon_contrib, coeff, out);
}

// Round 3
// 51.276 us; speedup vs baseline: 1.5741x; 1.3883x over previous
//
#include <hip/hip_runtime.h>
#include <hip/hip_bf16.h>
#include <math.h>

// Problem constants (from reference): B=2, P=10000, L=64, E=100
#define B_DIM 2
#define P_TOT 10000
#define L_DIM 64
#define E_DIM 100
#define THRESH 0.001f

// ---------------------------------------------------------------------------
// Kernel 1: fold all per-(b,e) math into 3 coefficients.
//   term(b,p,l,e) = exp2( d2*cA + sens*cS + L2F )
// coeff[e*2 + b] = {cA, cS, L2F, 0}
// ---------------------------------------------------------------------------
__global__ void axon_precompute(const float* __restrict__ stim,
                                const float* __restrict__ params,
                                float4* __restrict__ coeff) {
    int i = threadIdx.x;
    if (i >= B_DIM * E_DIM) return;
    int e = i >> 1;
    int b = i & 1;

    float freq = stim[(b * E_DIM + e) * 3 + 0];
    float amp  = stim[(b * E_DIM + e) * 3 + 1];
    float pdur = stim[(b * E_DIM + e) * 3 + 2];

    const float* pp = params + b * 12;
    float rho = pp[0], axl = pp[1];
    float a0 = pp[2], a1 = pp[3], a2 = pp[4], a3 = pp[5];
    float a5 = pp[7], a6 = pp[8], a7 = pp[9], a8 = pp[10], a9 = pp[11];

    float scaled = (a1 + a0 * pdur) * amp;
    float Fb = a2 * scaled + a3 * freq;
    if (!(scaled > 0.25f)) Fb = 0.f;   // AMP_CUTOFF
    if (!(amp > 0.f))      Fb = 0.f;   // !LIKE_JAX

    float rho2 = rho * rho;
    float Fsize = fmaxf(a5 * scaled + a6, 100.f / rho2);
    float axl2 = axl * axl;
    float Fstreak = fmaxf(a9 - a7 * powf(pdur, a8), 100.f / axl2);

    const float LOG2E = 1.4426950408889634f;
    float cA = -LOG2E / (2.f * rho2 * Fsize);
    float cS =  LOG2E / (axl2 * Fstreak);
    float L2F = (Fb > 0.f) ? log2f(Fb) : -1e30f;

    coeff[e * 2 + b] = make_float4(cA, cS, L2F, 0.f);
}

// ---------------------------------------------------------------------------
// Kernel 2: one block (256 thr = 4 waves) per pixel.
// Stage the pixel's contiguous 25.6 KB d2 block into LDS via
// global_load_lds (each instruction = coalesced 1 KB wave request),
// then thread t computes row l = t&63 over e-chunk q = t>>6
// (chunks 28/24/24/24, all 16B-aligned -> ds_read_b128 at word-stride 100
// = exactly 8 words/bank = conflict-free-equivalent).
// Coefficients are wave-uniform -> scalar loads.
// ---------------------------------------------------------------------------
__device__ __forceinline__ float4 lds_ld4(const float* p) {
    return *(const float4*)p;
}

template<int NE>
__device__ __forceinline__ void accum(const float* __restrict__ rowp,
                                      const float4* __restrict__ coeff,
                                      float sens, int ebase,
                                      float& s0, float& s1) {
    #pragma unroll
    for (int k4 = 0; k4 < NE / 4; ++k4) {
        float4 d2v = lds_ld4(rowp + k4 * 4);
        #pragma unroll
        for (int k = 0; k < 4; ++k) {
            int e = ebase + k4 * 4 + k;
            float d2 = (k == 0) ? d2v.x : (k == 1) ? d2v.y
                     : (k == 2) ? d2v.z : d2v.w;
            float4 c0 = coeff[e * 2 + 0];   // uniform -> s_load
            float4 c1 = coeff[e * 2 + 1];
            s0 += __builtin_amdgcn_exp2f(fmaf(d2, c0.x, fmaf(sens, c0.y, c0.z)));
            s1 += __builtin_amdgcn_exp2f(fmaf(d2, c1.x, fmaf(sens, c1.y, c1.z)));
        }
    }
}

__global__ __launch_bounds__(256) void axon_main(
    const float* __restrict__ d2_el,
    const float* __restrict__ axon_contrib,
    const float4* __restrict__ coeff,
    float* __restrict__ out) {

    __shared__ float  d2s[L_DIM * E_DIM];   // 6400 floats = 25.6 KB, linear [l][e]
    __shared__ float2 part[4][L_DIM];       // 2 KB

    int tid  = threadIdx.x;
    int lane = tid & 63;
    int q    = __builtin_amdgcn_readfirstlane(tid >> 6);  // wave id, SGPR
    int p    = blockIdx.x;

    // ---- stage: 25 x global_load_lds, chunks round-robined over waves ----
    const float* gbase = d2_el + (size_t)p * (L_DIM * E_DIM);
    for (int c = q; c < 25; c += 4) {
        const float* gp = gbase + c * 256 + lane * 4;   // per-lane 16B, contiguous 1KB/wave
        __builtin_amdgcn_global_load_lds(
            (const __attribute__((address_space(1))) float*)gp,
            (__attribute__((address_space(3))) float*)&d2s[c * 256],
            16, 0, 0);
    }

    // sens for this thread's row (tiny, 768B region per pixel)
    float sens = axon_contrib[((size_t)p * L_DIM + lane) * 3 + 2];

    __syncthreads();   // drains vmcnt -> LDS ready

    // ---- compute: row l = lane, e-chunk per wave: {0..27, 28..51, 52..75, 76..99}
    int ebase = (q == 0) ? 0 : (28 + (q - 1) * 24);
    const float* rowp = &d2s[lane * E_DIM + ebase];

    float s0 = 0.f, s1 = 0.f;
    if (q == 0) accum<28>(rowp, coeff, sens, ebase, s0, s1);
    else        accum<24>(rowp, coeff, sens, ebase, s0, s1);

    part[q][lane] = make_float2(s0, s1);
    __syncthreads();

    // ---- wave 0: combine quarters, max over l, write both batches ----
    if (tid < 64) {
        float2 p0 = part[0][tid], p1 = part[1][tid];
        float2 p2 = part[2][tid], p3 = part[3][tid];
        float r0 = (p0.x + p1.x) + (p2.x + p3.x);
        float r1 = (p0.y + p1.y) + (p2.y + p3.y);
        #pragma unroll
        for (int off = 32; off; off >>= 1) {
            r0 = fmaxf(r0, __shfl_xor(r0, off, 64));
            r1 = fmaxf(r1, __shfl_xor(r1, off, 64));
        }
        if (tid == 0) {
            out[p]         = (r0 > THRESH) ? r0 : 0.f;
            out[P_TOT + p] = (r1 > THRESH) ? r1 : 0.f;
        }
    }
}

extern "C" void kernel_launch(void* const* d_in, const int* in_sizes, int n_in,
                              void* d_out, int out_size, void* d_ws, size_t ws_size,
                              hipStream_t stream) {
    const float* stim         = (const float*)d_in[0];  // (B,E,3)
    const float* params       = (const float*)d_in[1];  // (B,12)
    const float* axon_contrib = (const float*)d_in[2];  // (P,L,3)
    const float* d2_el        = (const float*)d_in[3];  // (P,L,E)
    float* out = (float*)d_out;                         // (B,P) = 20000 floats
    float4* coeff = (float4*)d_ws;                      // 200 float4 = 3200 B

    axon_precompute<<<1, 256, 0, stream>>>(stim, params, coeff);
    axon_main<<<P_TOT, 256, 0, stream>>>(d2_el, axon_contrib, coeff, out);
}